// Round 3
// baseline (534.405 us; speedup 1.0000x reference)
//
#include <hip/hip_runtime.h>
#include <hip/hip_bf16.h>

typedef __attribute__((ext_vector_type(8))) __bf16 bf16x8;
typedef __attribute__((ext_vector_type(2))) __bf16 bf16x2;
typedef __attribute__((ext_vector_type(4))) float f32x4;

#define B_   16
#define C_   128
#define DIM  24
#define F_   128
#define OD   22
#define OS   (OD*OD*OD)        // 10648
#define SPB  (DIM*DIM*DIM)     // 13824 spatial per (b)
#define K_   3456              // 128*27
#define M_   (B_*OS)           // 170368
#define OUTN (B_*F_*OS)        // 21807104

// ---------------- async global->LDS (16B per lane, wave-uniform LDS base) ---
__device__ __forceinline__ void async16(const void* g, void* l) {
  __builtin_amdgcn_global_load_lds(
      (const __attribute__((address_space(1))) unsigned int*)g,
      (__attribute__((address_space(3))) unsigned int*)l, 16, 0, 0);
}

// tap offsets dz*576+dy*24+dx for the 27 kernel positions
__device__ __constant__ int DOFF[27] = {
    0,    1,    2,    24,   25,   26,   48,   49,   50,
    576,  577,  578,  600,  601,  602,  624,  625,  626,
    1152, 1153, 1154, 1176, 1177, 1178, 1200, 1201, 1202};

// ---------------- kernel 1: xs -> channels-last bf16 xt, plus sum_c x^2 -----
__global__ __launch_bounds__(256) void prep_x(const float* __restrict__ xs,
                                              __bf16* __restrict__ xt,
                                              float* __restrict__ s1) {
  __shared__ float tile[C_ * 97];            // 49.7 KB
  __shared__ float red[192];
  const int blk = blockIdx.x;                // (b*24+z)*6+yg, 2304 blocks
  const int yg = blk % 6;
  const int t2 = blk / 6;
  const int z = t2 % DIM;
  const int b = t2 / DIM;
  const int t = threadIdx.x;
  const float* src = xs + (size_t)b * C_ * SPB + z * (DIM * DIM) + yg * 96;
  for (int it = 0; it < 12; ++it) {
    int idx = it * 256 + t;
    int c = idx / 24, f4 = idx - c * 24;
    const float4 v = *(const float4*)(src + (size_t)c * SPB + f4 * 4);
    float* d = &tile[c * 97 + f4 * 4];
    d[0] = v.x; d[1] = v.y; d[2] = v.z; d[3] = v.w;
  }
  __syncthreads();
  size_t obase = ((size_t)b * SPB + z * (DIM * DIM) + yg * 96) * C_;
  for (int it = 0; it < 24; ++it) {
    int idx = it * 256 + t;
    int c2 = idx & 63, x = idx >> 6;
    bf16x2 v;
    v[0] = (__bf16)tile[(2 * c2) * 97 + x];
    v[1] = (__bf16)tile[(2 * c2 + 1) * 97 + x];
    *(bf16x2*)&xt[obase + (size_t)x * C_ + 2 * c2] = v;
  }
  if (t < 192) {
    int g = t / 96, p = t - g * 96;
    float s = 0.f;
    for (int c = g; c < C_; c += 2) {
      float v = tile[c * 97 + p];
      s += v * v;
    }
    red[g * 96 + p] = s;
  }
  __syncthreads();
  if (t < 96)
    s1[((size_t)b * SPB + z * (DIM * DIM) + yg * 96) + t] = red[t] + red[96 + t];
}

// ---------------- kernel 2: weights -> Wt[f][off*128+c] bf16, plus ||p||^2 --
__global__ void prep_w(const float* __restrict__ fv, __bf16* __restrict__ Wt,
                       float* __restrict__ psq) {
  __shared__ float tile[K_];                 // 13.8 KB
  const int f = blockIdx.x;                  // 128 blocks
  const float* src = fv + (size_t)f * K_;
  float part = 0.f;
  for (int idx = threadIdx.x; idx < K_; idx += 256) {
    float v = src[idx];
    tile[idx] = v;
    part += v * v;
  }
  __syncthreads();
  for (int idx = threadIdx.x; idx < K_; idx += 256) {
    int c = idx & 127, off = idx >> 7;       // k = off*128 + c
    Wt[(size_t)f * K_ + idx] = (__bf16)tile[c * 27 + off];
  }
  for (int o = 32; o > 0; o >>= 1) part += __shfl_down(part, o, 64);
  __shared__ float red[4];
  int w = threadIdx.x >> 6, l = threadIdx.x & 63;
  if (l == 0) red[w] = part;
  __syncthreads();
  if (threadIdx.x == 0) psq[f] = red[0] + red[1] + red[2] + red[3];
}

// ---------------- kernel 3: 3x3x3 valid sum-pool of s1 ----------------------
__global__ void pool_sq(const float* __restrict__ s1, float* __restrict__ xsq) {
  int i = blockIdx.x * 256 + threadIdx.x;
  if (i >= M_) return;
  int ow = i % OD;
  int t = i / OD;
  int oh = t % OD; t /= OD;
  int od = t % OD;
  int b = t / OD;
  const float* p = s1 + ((b * DIM + od) * DIM + oh) * DIM + ow;
  float s = 0.f;
#pragma unroll
  for (int dz = 0; dz < 3; ++dz)
#pragma unroll
    for (int dy = 0; dy < 3; ++dy)
#pragma unroll
      for (int dx = 0; dx < 3; ++dx)
        s += p[dz * 576 + dy * 24 + dx];
  xsq[i] = s;
}

// ---------------- kernel 4: implicit-GEMM MFMA + fused L2 epilogue ----------
// Tile 128f x 256m, BK=64. Wave tile 64f x 128m (4x8 fragments, 128 AGPRs).
// 12 fragment ds_read_b128 -> 32 MFMAs per wave-kk (2.67 MFMA/read vs 2.0 of
// the 128x128 tile) — moves the binding pipe from LDS-read to MFMA.
// XOR chunk swizzle (R2) keeps LDS conflict-free: chunk e of row r lives at
// slot e^(r&7); staging permutes the GLOBAL source chunk.
__global__ __launch_bounds__(256) void l2gemm(
    const __bf16* __restrict__ xt, const __bf16* __restrict__ Wt,
    const float* __restrict__ xsq, const float* __restrict__ psq,
    float* __restrict__ out) {
  __shared__ __align__(16) __bf16 Wl[128 * 64];   // 16 KB
  __shared__ __align__(16) __bf16 Pl[256 * 64];   // 32 KB
  const int t = threadIdx.x;
  const int l = t & 63, w = t >> 6;
  const int quad = l >> 4, lan = l & 15;
  const int e = t & 7, r0 = t >> 3;     // staging: chunk e (16B) of row r0+32p
  const int esw = (e ^ (r0 & 7)) * 8;   // XOR-swizzled source chunk (bf16 units)
  const int mt = blockIdx.x;

  // spatial base (element index into xt / 128ch) for the 8 staged patch rows
  int sb[8];
#pragma unroll
  for (int p = 0; p < 8; ++p) {
    int m = mt * 256 + r0 + 32 * p;
    if (m >= M_) m = M_ - 1;          // clamp: last (half) tile stages valid mem
    int b = m / OS;
    int s = m - b * OS;
    int od = s / (OD * OD);
    int s2 = s - od * (OD * OD);
    int oh = s2 / OD;
    int ow = s2 - oh * OD;
    sb[p] = b * SPB + od * 576 + oh * 24 + ow;
  }

  f32x4 acc[4][8];
#pragma unroll
  for (int i = 0; i < 4; ++i)
#pragma unroll
    for (int n = 0; n < 8; ++n) acc[i][n] = (f32x4){0.f, 0.f, 0.f, 0.f};

  const int wm = (w >> 1) * 64;    // f-offset of this wave's 64x128 subtile
  const int wn = (w & 1) * 128;    // patch-offset
  __bf16* wl_base = &Wl[(w * 8) * 64];
  __bf16* pl_base = &Pl[(w * 8) * 64];

#pragma unroll 1
  for (int kt = 0; kt < 54; ++kt) {
    int doff = DOFF[kt >> 1];
    int c0 = (kt & 1) << 6;
    __syncthreads();   // previous tile's compute done before overwrite
#pragma unroll
    for (int p = 0; p < 8; ++p) {
      const __bf16* gp = xt + (((size_t)(sb[p] + doff)) << 7) + c0 + esw;
      async16(gp, pl_base + (size_t)(32 * p) * 64);
    }
#pragma unroll
    for (int p = 0; p < 4; ++p) {
      const __bf16* gw = Wt + (size_t)(r0 + 32 * p) * K_ + kt * 64 + esw;
      async16(gw, wl_base + (size_t)(32 * p) * 64);
    }
    __syncthreads();   // compiler drains vmcnt before s_barrier
#pragma unroll
    for (int kk = 0; kk < 2; ++kk) {
      bf16x8 a[4], bb[8];
      const int swz = (((kk * 4 + quad) ^ (lan & 7))) * 8;  // read-side XOR
#pragma unroll
      for (int i = 0; i < 4; ++i)
        a[i] = *(const bf16x8*)&Wl[(wm + i * 16 + lan) * 64 + swz];
#pragma unroll
      for (int n = 0; n < 8; ++n)
        bb[n] = *(const bf16x8*)&Pl[(wn + n * 16 + lan) * 64 + swz];
#pragma unroll
      for (int i = 0; i < 4; ++i)
#pragma unroll
        for (int n = 0; n < 8; ++n)
          acc[i][n] = __builtin_amdgcn_mfma_f32_16x16x32_bf16(a[i], bb[n],
                                                              acc[i][n], 0, 0, 0);
    }
  }

  // epilogue: out[b][f][s] = sqrt(|xsq + psq - 2*dot| + eps)
  int mb[8];
  float xv[8];
  bool ok[8];
#pragma unroll
  for (int n = 0; n < 8; ++n) {
    int m = mt * 256 + wn + n * 16 + lan;
    ok[n] = (m < M_);
    int mc = ok[n] ? m : (M_ - 1);
    int b = mc / OS;
    int s = mc - b * OS;
    mb[n] = b * (F_ * OS) + s;
    xv[n] = xsq[mc];
  }
#pragma unroll
  for (int i = 0; i < 4; ++i) {
#pragma unroll
    for (int r = 0; r < 4; ++r) {
      int f = wm + i * 16 + quad * 4 + r;
      float pq = psq[f];
#pragma unroll
      for (int n = 0; n < 8; ++n) {
        if (ok[n]) {
          float d = xv[n] + pq - 2.0f * acc[i][n][r];
          out[mb[n] + f * OS] = sqrtf(fabsf(d) + 1e-14f);
        }
      }
    }
  }
}

// ---------------- fallback: direct fp32 conv (only if ws too small) ---------
__global__ void l2conv_direct(const float* __restrict__ xs,
                              const float* __restrict__ fv,
                              float* __restrict__ out) {
  int i = blockIdx.x * 256 + threadIdx.x;
  if (i >= OUTN) return;
  int s = i % OS;
  int t2 = i / OS;
  int f = t2 & 127;
  int b = t2 >> 7;
  int od = s / (OD * OD);
  int s2 = s - od * (OD * OD);
  int oh = s2 / OD;
  int ow = s2 - oh * OD;
  const float* xp = xs + (size_t)b * C_ * SPB + od * 576 + oh * 24 + ow;
  const float* wp = fv + (size_t)f * K_;
  float dot = 0.f, xq = 0.f, pq = 0.f;
  for (int c = 0; c < C_; ++c) {
    const float* xpc = xp + (size_t)c * SPB;
    const float* wpc = wp + c * 27;
#pragma unroll
    for (int o = 0; o < 27; ++o) {
      int dz = o / 9;
      int ry = o - dz * 9;
      int dy = ry / 3;
      int dx = ry - dy * 3;
      float xv = xpc[dz * 576 + dy * 24 + dx];
      float wv = wpc[o];
      dot += xv * wv;
      xq += xv * xv;
      pq += wv * wv;
    }
  }
  out[i] = sqrtf(fabsf(xq + pq - 2.f * dot) + 1e-14f);
}

// ---------------- launch ----------------------------------------------------
extern "C" void kernel_launch(void* const* d_in, const int* in_sizes, int n_in,
                              void* d_out, int out_size, void* d_ws,
                              size_t ws_size, hipStream_t stream) {
  const float* xs = (const float*)d_in[0];
  const float* fv = (const float*)d_in[1];
  float* out = (float*)d_out;

  const size_t xt_b  = (size_t)B_ * SPB * C_ * 2;   // 56,623,104
  const size_t wt_b  = (size_t)F_ * K_ * 2;         //    884,736
  const size_t s1_b  = (size_t)B_ * SPB * 4;        //    884,736
  const size_t xsq_b = (size_t)M_ * 4;              //    681,472
  const size_t psq_b = 512;
  if (ws_size < xt_b + wt_b + s1_b + xsq_b + psq_b) {
    l2conv_direct<<<(OUTN + 255) / 256, 256, 0, stream>>>(xs, fv, out);
    return;
  }
  char* p = (char*)d_ws;
  __bf16* xt = (__bf16*)p;          p += xt_b;
  __bf16* Wt = (__bf16*)p;          p += wt_b;
  float*  s1 = (float*)p;           p += s1_b;
  float*  xsq = (float*)p;          p += xsq_b;
  float*  psq = (float*)p;

  prep_x<<<B_ * DIM * DIM / 4, 256, 0, stream>>>(xs, xt, s1);
  prep_w<<<F_, 256, 0, stream>>>(fv, Wt, psq);
  pool_sq<<<(M_ + 255) / 256, 256, 0, stream>>>(s1, xsq);
  l2gemm<<<(M_ + 255) / 256, 256, 0, stream>>>(xt, Wt, xsq, psq, out);
}

// Round 4
// 412.931 us; speedup vs baseline: 1.2942x; 1.2942x over previous
//
#include <hip/hip_runtime.h>
#include <hip/hip_bf16.h>

typedef __attribute__((ext_vector_type(8))) __bf16 bf16x8;
typedef __attribute__((ext_vector_type(2))) __bf16 bf16x2;
typedef __attribute__((ext_vector_type(4))) float f32x4;

#define B_   16
#define C_   128
#define DIM  24
#define F_   128
#define OD   22
#define OS   (OD*OD*OD)        // 10648
#define SPB  (DIM*DIM*DIM)     // 13824 spatial per (b)
#define K_   3456              // 128*27
#define M_   (B_*OS)           // 170368
#define OUTN (B_*F_*OS)        // 21807104
#define NMT  666               // ceil(M_/256)

// ---------------- async global->LDS (16B per lane, wave-uniform LDS base) ---
__device__ __forceinline__ void async16(const void* g, void* l) {
  __builtin_amdgcn_global_load_lds(
      (const __attribute__((address_space(1))) unsigned int*)g,
      (__attribute__((address_space(3))) unsigned int*)l, 16, 0, 0);
}

// tap offsets dz*576+dy*24+dx for the 27 kernel positions
__device__ __constant__ int DOFF[27] = {
    0,    1,    2,    24,   25,   26,   48,   49,   50,
    576,  577,  578,  600,  601,  602,  624,  625,  626,
    1152, 1153, 1154, 1176, 1177, 1178, 1200, 1201, 1202};

// ---------------- kernel 1: xs -> channels-last bf16 xt, plus sum_c x^2 -----
__global__ __launch_bounds__(256) void prep_x(const float* __restrict__ xs,
                                              __bf16* __restrict__ xt,
                                              float* __restrict__ s1) {
  __shared__ float tile[C_ * 97];            // 49.7 KB
  __shared__ float red[192];
  const int blk = blockIdx.x;                // (b*24+z)*6+yg, 2304 blocks
  const int yg = blk % 6;
  const int t2 = blk / 6;
  const int z = t2 % DIM;
  const int b = t2 / DIM;
  const int t = threadIdx.x;
  const float* src = xs + (size_t)b * C_ * SPB + z * (DIM * DIM) + yg * 96;
  for (int it = 0; it < 12; ++it) {
    int idx = it * 256 + t;
    int c = idx / 24, f4 = idx - c * 24;
    const float4 v = *(const float4*)(src + (size_t)c * SPB + f4 * 4);
    float* d = &tile[c * 97 + f4 * 4];
    d[0] = v.x; d[1] = v.y; d[2] = v.z; d[3] = v.w;
  }
  __syncthreads();
  size_t obase = ((size_t)b * SPB + z * (DIM * DIM) + yg * 96) * C_;
  for (int it = 0; it < 24; ++it) {
    int idx = it * 256 + t;
    int c2 = idx & 63, x = idx >> 6;
    bf16x2 v;
    v[0] = (__bf16)tile[(2 * c2) * 97 + x];
    v[1] = (__bf16)tile[(2 * c2 + 1) * 97 + x];
    *(bf16x2*)&xt[obase + (size_t)x * C_ + 2 * c2] = v;
  }
  if (t < 192) {
    int g = t / 96, p = t - g * 96;
    float s = 0.f;
    for (int c = g; c < C_; c += 2) {
      float v = tile[c * 97 + p];
      s += v * v;
    }
    red[g * 96 + p] = s;
  }
  __syncthreads();
  if (t < 96)
    s1[((size_t)b * SPB + z * (DIM * DIM) + yg * 96) + t] = red[t] + red[96 + t];
}

// ---------------- kernel 2 (fused): pool_sq (blocks 0..665) + prep_w --------
__global__ __launch_bounds__(256) void pool_prepw(
    const float* __restrict__ s1, float* __restrict__ xsq,
    const float* __restrict__ fv, __bf16* __restrict__ Wt,
    float* __restrict__ psq) {
  if (blockIdx.x >= NMT) {
    // ---- prep_w for filter f ----
    __shared__ float tile[K_];               // 13.8 KB
    const int f = blockIdx.x - NMT;          // 128 blocks
    const float* src = fv + (size_t)f * K_;
    float part = 0.f;
    for (int idx = threadIdx.x; idx < K_; idx += 256) {
      float v = src[idx];
      tile[idx] = v;
      part += v * v;
    }
    __syncthreads();
    for (int idx = threadIdx.x; idx < K_; idx += 256) {
      int c = idx & 127, off = idx >> 7;     // k = off*128 + c
      Wt[(size_t)f * K_ + idx] = (__bf16)tile[c * 27 + off];
    }
    for (int o = 32; o > 0; o >>= 1) part += __shfl_down(part, o, 64);
    __shared__ float red[4];
    int w = threadIdx.x >> 6, l = threadIdx.x & 63;
    if (l == 0) red[w] = part;
    __syncthreads();
    if (threadIdx.x == 0) psq[f] = red[0] + red[1] + red[2] + red[3];
    return;
  }
  // ---- 3x3x3 valid sum-pool of s1 ----
  int i = blockIdx.x * 256 + threadIdx.x;
  if (i >= M_) return;
  int ow = i % OD;
  int t = i / OD;
  int oh = t % OD; t /= OD;
  int od = t % OD;
  int b = t / OD;
  const float* p = s1 + ((b * DIM + od) * DIM + oh) * DIM + ow;
  float s = 0.f;
#pragma unroll
  for (int dz = 0; dz < 3; ++dz)
#pragma unroll
    for (int dy = 0; dy < 3; ++dy)
#pragma unroll
      for (int dx = 0; dx < 3; ++dx)
        s += p[dz * 576 + dy * 24 + dx];
  xsq[i] = s;
}

// ---------------- kernel 3: implicit-GEMM MFMA + fused L2 epilogue ----------
// Tile 128f x 256m, BK=64. Wave tile 64f x 128m (4x8 frags = 128 AGPR).
// __launch_bounds__(256,2) caps unified regs at 256/wave (128 AGPR + <=128
// VGPR) -> 2 waves/SIMD, 2 blocks/CU. (R3 failed here: 160 VGPR + 128 AGPR
// = 288 -> 1 wave/SIMD -> no latency hiding.)
// XOR chunk swizzle keeps LDS conflict-free: chunk e of row r at slot e^(r&7),
// permuted on the GLOBAL source side (global_load_lds dest is lane-contiguous).
// Block swizzle: mt=(bid&7)*84+(bid>>3) keeps ~84 consecutive m-tiles (which
// share 26/27 patch taps) on one XCD's L2.
__global__ __launch_bounds__(256, 2) void l2gemm(
    const __bf16* __restrict__ xt, const __bf16* __restrict__ Wt,
    const float* __restrict__ xsq, const float* __restrict__ psq,
    float* __restrict__ out) {
  __shared__ __align__(16) __bf16 Wl[128 * 64];   // 16 KB
  __shared__ __align__(16) __bf16 Pl[256 * 64];   // 32 KB
  const int mt = (blockIdx.x & 7) * 84 + (blockIdx.x >> 3);
  if (mt >= NMT) return;
  const int t = threadIdx.x;
  const int l = t & 63, w = t >> 6;
  const int quad = l >> 4, lan = l & 15;
  const int e = t & 7, r0 = t >> 3;     // staging: chunk e (16B) of row r0+32p
  const int esw = (e ^ (r0 & 7)) * 8;   // XOR-swizzled source chunk (bf16 units)

  // spatial base (element index into xt / 128ch) for the 8 staged patch rows
  int sb[8];
#pragma unroll
  for (int p = 0; p < 8; ++p) {
    int m = mt * 256 + r0 + 32 * p;
    if (m >= M_) m = M_ - 1;          // clamp: tail tile stages valid memory
    int b = m / OS;
    int s = m - b * OS;
    int od = s / (OD * OD);
    int s2 = s - od * (OD * OD);
    int oh = s2 / OD;
    int ow = s2 - oh * OD;
    sb[p] = b * SPB + od * 576 + oh * 24 + ow;
  }

  f32x4 acc[4][8];
#pragma unroll
  for (int i = 0; i < 4; ++i)
#pragma unroll
    for (int n = 0; n < 8; ++n) acc[i][n] = (f32x4){0.f, 0.f, 0.f, 0.f};

  const int wm = (w >> 1) * 64;    // f-offset of this wave's 64x128 subtile
  const int wn = (w & 1) * 128;    // patch-offset
  __bf16* wl_base = &Wl[(w * 8) * 64];
  __bf16* pl_base = &Pl[(w * 8) * 64];

#pragma unroll 1
  for (int kt = 0; kt < 54; ++kt) {
    int doff = DOFF[kt >> 1];
    int c0 = (kt & 1) << 6;
    __syncthreads();   // previous tile's compute done before overwrite
#pragma unroll
    for (int p = 0; p < 8; ++p) {
      const __bf16* gp = xt + (((size_t)(sb[p] + doff)) << 7) + c0 + esw;
      async16(gp, pl_base + (size_t)(32 * p) * 64);
    }
#pragma unroll
    for (int p = 0; p < 4; ++p) {
      const __bf16* gw = Wt + (size_t)(r0 + 32 * p) * K_ + kt * 64 + esw;
      async16(gw, wl_base + (size_t)(32 * p) * 64);
    }
    __syncthreads();   // compiler drains vmcnt before s_barrier
#pragma unroll
    for (int kk = 0; kk < 2; ++kk) {
      bf16x8 a[4], bb[8];
      const int swz = (((kk * 4 + quad) ^ (lan & 7))) * 8;  // read-side XOR
#pragma unroll
      for (int i = 0; i < 4; ++i)
        a[i] = *(const bf16x8*)&Wl[(wm + i * 16 + lan) * 64 + swz];
#pragma unroll
      for (int n = 0; n < 8; ++n)
        bb[n] = *(const bf16x8*)&Pl[(wn + n * 16 + lan) * 64 + swz];
#pragma unroll
      for (int i = 0; i < 4; ++i)
#pragma unroll
        for (int n = 0; n < 8; ++n)
          acc[i][n] = __builtin_amdgcn_mfma_f32_16x16x32_bf16(a[i], bb[n],
                                                              acc[i][n], 0, 0, 0);
    }
  }

  // epilogue: out[b][f][s] = sqrt(|xsq + psq - 2*dot| + eps)
  int mb[8];
  float xv[8];
  bool ok[8];
#pragma unroll
  for (int n = 0; n < 8; ++n) {
    int m = mt * 256 + wn + n * 16 + lan;
    ok[n] = (m < M_);
    int mc = ok[n] ? m : (M_ - 1);
    int b = mc / OS;
    int s = mc - b * OS;
    mb[n] = b * (F_ * OS) + s;
    xv[n] = xsq[mc];
  }
#pragma unroll
  for (int i = 0; i < 4; ++i) {
#pragma unroll
    for (int r = 0; r < 4; ++r) {
      int f = wm + i * 16 + quad * 4 + r;
      float pq = psq[f];
#pragma unroll
      for (int n = 0; n < 8; ++n) {
        if (ok[n]) {
          float d = xv[n] + pq - 2.0f * acc[i][n][r];
          out[mb[n] + f * OS] = sqrtf(fabsf(d) + 1e-14f);
        }
      }
    }
  }
}

// ---------------- fallback: direct fp32 conv (only if ws too small) ---------
__global__ void l2conv_direct(const float* __restrict__ xs,
                              const float* __restrict__ fv,
                              float* __restrict__ out) {
  int i = blockIdx.x * 256 + threadIdx.x;
  if (i >= OUTN) return;
  int s = i % OS;
  int t2 = i / OS;
  int f = t2 & 127;
  int b = t2 >> 7;
  int od = s / (OD * OD);
  int s2 = s - od * (OD * OD);
  int oh = s2 / OD;
  int ow = s2 - oh * OD;
  const float* xp = xs + (size_t)b * C_ * SPB + od * 576 + oh * 24 + ow;
  const float* wp = fv + (size_t)f * K_;
  float dot = 0.f, xq = 0.f, pq = 0.f;
  for (int c = 0; c < C_; ++c) {
    const float* xpc = xp + (size_t)c * SPB;
    const float* wpc = wp + c * 27;
#pragma unroll
    for (int o = 0; o < 27; ++o) {
      int dz = o / 9;
      int ry = o - dz * 9;
      int dy = ry / 3;
      int dx = ry - dy * 3;
      float xv = xpc[dz * 576 + dy * 24 + dx];
      float wv = wpc[o];
      dot += xv * wv;
      xq += xv * xv;
      pq += wv * wv;
    }
  }
  out[i] = sqrtf(fabsf(xq + pq - 2.f * dot) + 1e-14f);
}

// ---------------- launch ----------------------------------------------------
extern "C" void kernel_launch(void* const* d_in, const int* in_sizes, int n_in,
                              void* d_out, int out_size, void* d_ws,
                              size_t ws_size, hipStream_t stream) {
  const float* xs = (const float*)d_in[0];
  const float* fv = (const float*)d_in[1];
  float* out = (float*)d_out;

  const size_t xt_b  = (size_t)B_ * SPB * C_ * 2;   // 56,623,104
  const size_t wt_b  = (size_t)F_ * K_ * 2;         //    884,736
  const size_t s1_b  = (size_t)B_ * SPB * 4;        //    884,736
  const size_t xsq_b = (size_t)M_ * 4;              //    681,472
  const size_t psq_b = 512;
  if (ws_size < xt_b + wt_b + s1_b + xsq_b + psq_b) {
    l2conv_direct<<<(OUTN + 255) / 256, 256, 0, stream>>>(xs, fv, out);
    return;
  }
  char* p = (char*)d_ws;
  __bf16* xt = (__bf16*)p;          p += xt_b;
  __bf16* Wt = (__bf16*)p;          p += wt_b;
  float*  s1 = (float*)p;           p += s1_b;
  float*  xsq = (float*)p;          p += xsq_b;
  float*  psq = (float*)p;

  prep_x<<<B_ * DIM * DIM / 4, 256, 0, stream>>>(xs, xt, s1);
  pool_prepw<<<NMT + 128, 256, 0, stream>>>(s1, xsq, fv, Wt, psq);
  l2gemm<<<672, 256, 0, stream>>>(xt, Wt, xsq, psq, out);
}